// Round 1
// 242.878 us; speedup vs baseline: 1.0157x; 1.0157x over previous
//
#include <hip/hip_runtime.h>
#include <stdint.h>
#include <math.h>

typedef __bf16 bf16;
typedef __bf16 bf16x4 __attribute__((ext_vector_type(4)));
typedef __bf16 bf16x8 __attribute__((ext_vector_type(8)));
typedef float floatx4 __attribute__((ext_vector_type(4)));

#define CEXP 0.1803368801111204f  /* (1/8) * log2(e) */

// ---------------------------------------------------------------------------
// Weight pre-convert: fp32 [1024][1024] -> bf16, 4 matrices (Wq,Wk,Wv,Wo)
// ---------------------------------------------------------------------------
__global__ __launch_bounds__(256) void wcvt_kernel(
    const float* __restrict__ Wq, const float* __restrict__ Wk,
    const float* __restrict__ Wv, const float* __restrict__ Wo,
    bf16* __restrict__ dst)
{
  const float* src = (blockIdx.y == 0) ? Wq : (blockIdx.y == 1) ? Wk
                   : (blockIdx.y == 2) ? Wv : Wo;
  bf16* d = dst + (size_t)blockIdx.y * 1048576;
  const int i = (blockIdx.x * 256 + threadIdx.x) * 4;
  const floatx4 v = *(const floatx4*)(src + i);
  bf16x4 o;
#pragma unroll
  for (int j = 0; j < 4; ++j) o[j] = (bf16)v[j];
  *(bf16x4*)(d + i) = o;
}

// ---------------------------------------------------------------------------
// GEMM: C[4096,1024] = A @ Wb(bf16)^T + bias(fp32)
// 128x128 tile, BK=64, 4 waves, register-prefetch pipeline, LDS stride 72.
// Grid is M-MAJOR (x=m,y=n): same-m blocks land on one XCD -> A cached in L2.
// mode 0: A fp32 direct; C bf16 [b,h,s,dk]
// mode 2: A fp32 direct; C bf16 [b,h,dk,s] (transposed V) — epilogue goes
//         through LDS so global stores are 16B-coalesced (old path was 64
//         scattered 2B stores per lane).
// mode 1: A bf16 gathered from Sb [b,h,s,dk]; C fp32 [token][col]
// ---------------------------------------------------------------------------
__device__ __forceinline__ void gemm_body(
    const float* __restrict__ A, const bf16* __restrict__ Ab,
    const bf16* __restrict__ Wb, const float* __restrict__ bias,
    void* __restrict__ Cout, const int mode, const float oscale)
{
  __shared__ __align__(16) bf16 As[128 * 72];
  __shared__ __align__(16) bf16 Bs[128 * 72];
  const int tid  = threadIdx.x;
  const int wave = tid >> 6;
  const int lane = tid & 63;
  const int mlane = lane & 15;
  const int quad  = lane >> 4;
  const int m0 = blockIdx.x * 128;   // m-major grid
  const int n0 = blockIdx.y * 128;
  const int wm = (wave >> 1) * 64;
  const int wn = (wave & 1) * 64;
  const int arow = tid >> 4, ac4 = (tid & 15) * 4;  // fp32 A: 16 rows/pass
  const int wrow = tid >> 3, wc8 = (tid & 7) * 8;   // bf16: 32 rows/pass

  floatx4 a_pf[8];
  bf16x8  ab_pf[4];
  bf16x8  w_pf[4];

  auto load_a = [&](int k0) {
    if (mode == 1) {
#pragma unroll
      for (int c = 0; c < 4; ++c) {
        const int token = m0 + c * 32 + wrow;
        const int b = token >> 11, s = token & 2047;
        const int h = k0 >> 6;  // BK=64 stays within one head
        ab_pf[c] = *(const bf16x8*)(Ab + (((size_t)(b * 16 + h) * 2048 + s) << 6) + wc8);
      }
    } else {
#pragma unroll
      for (int rr = 0; rr < 8; ++rr)
        a_pf[rr] = *(const floatx4*)(A + (size_t)(m0 + rr * 16 + arow) * 1024 + k0 + ac4);
    }
  };
  auto load_w = [&](int k0) {
#pragma unroll
    for (int c = 0; c < 4; ++c)
      w_pf[c] = *(const bf16x8*)(Wb + (size_t)(n0 + c * 32 + wrow) * 1024 + k0 + wc8);
  };

  load_a(0);
  load_w(0);

  floatx4 acc[4][4] = {};

  for (int k0 = 0; k0 < 1024; k0 += 64) {
    if (mode == 1) {
#pragma unroll
      for (int c = 0; c < 4; ++c)
        *(bf16x8*)&As[(c * 32 + wrow) * 72 + wc8] = ab_pf[c];
    } else {
#pragma unroll
      for (int rr = 0; rr < 8; ++rr) {
        bf16x4 ac;
#pragma unroll
        for (int j = 0; j < 4; ++j) ac[j] = (bf16)a_pf[rr][j];
        *(bf16x4*)&As[(rr * 16 + arow) * 72 + ac4] = ac;
      }
    }
#pragma unroll
    for (int c = 0; c < 4; ++c)
      *(bf16x8*)&Bs[(c * 32 + wrow) * 72 + wc8] = w_pf[c];
    __syncthreads();

    if (k0 + 64 < 1024) { load_a(k0 + 64); load_w(k0 + 64); }

#pragma unroll
    for (int kk = 0; kk < 64; kk += 32) {
      bf16x8 af[4], bfr[4];
#pragma unroll
      for (int t = 0; t < 4; ++t) {
        af[t]  = *(const bf16x8*)&As[(wm + t * 16 + mlane) * 72 + kk + quad * 8];
        bfr[t] = *(const bf16x8*)&Bs[(wn + t * 16 + mlane) * 72 + kk + quad * 8];
      }
#pragma unroll
      for (int mt = 0; mt < 4; ++mt)
#pragma unroll
        for (int nt = 0; nt < 4; ++nt)
          acc[mt][nt] = __builtin_amdgcn_mfma_f32_16x16x32_bf16(
              af[mt], bfr[nt], acc[mt][nt], 0, 0, 0);
    }
    __syncthreads();
  }

  // epilogue
  if (mode == 2) {
    // Transpose the wave's 64x64 tile through LDS (As/Bs are free after the
    // final __syncthreads of the K-loop), then store 16B contiguous chunks:
    // 8 lanes cover a 128B run of one dk-row of V^T.
    bf16* T = (wave < 2) ? &As[wave * 4608] : &Bs[(wave - 2) * 4608];
#pragma unroll
    for (int nt = 0; nt < 4; ++nt) {
      const float bv = bias[n0 + wn + nt * 16 + mlane];
#pragma unroll
      for (int mt = 0; mt < 4; ++mt) {
        bf16x4 t4;
#pragma unroll
        for (int r = 0; r < 4; ++r)
          t4[r] = (bf16)((acc[mt][nt][r] + bv) * oscale);
        // T[col_local][row_local], stride 72 (16B-aligned rows, b64 writes)
        *(bf16x4*)&T[(nt * 16 + mlane) * 72 + mt * 16 + quad * 4] = t4;
      }
    }
    asm volatile("s_waitcnt lgkmcnt(0)" ::: "memory");  // wave-local transpose
    const int token0 = m0 + wm;            // 64-aligned -> single b
    const int bb = token0 >> 11;
    const int srow0 = token0 & 2047;
    const int h = (n0 + wn) >> 6;          // 64-aligned -> single h
    const int dl = lane >> 3;
    const int s8 = (lane & 7) * 8;
    bf16* outp = (bf16*)Cout + ((size_t)(bb * 16 + h) << 17);
#pragma unroll
    for (int p = 0; p < 8; ++p) {
      const int dk = p * 8 + dl;
      const bf16x8 v8 = *(const bf16x8*)&T[dk * 72 + s8];
      *(bf16x8*)&outp[((size_t)dk << 11) + srow0 + s8] = v8;
    }
    return;
  }

#pragma unroll
  for (int nt = 0; nt < 4; ++nt) {
    const int col = n0 + wn + nt * 16 + mlane;
    const float bv = bias[col];
#pragma unroll
    for (int mt = 0; mt < 4; ++mt) {
#pragma unroll
      for (int r = 0; r < 4; ++r) {
        const int row = m0 + wm + mt * 16 + quad * 4 + r;
        const float v = (acc[mt][nt][r] + bv) * oscale;
        if (mode == 0) {
          const int b = row >> 11, s = row & 2047;
          const int h = col >> 6, dk = col & 63;
          ((bf16*)Cout)[(((size_t)(b * 16 + h) * 2048 + s) << 6) + dk] = (bf16)v;
        } else {
          ((float*)Cout)[(size_t)row * 1024 + col] = v;
        }
      }
    }
  }
}

__global__ __launch_bounds__(256) void qkv_kernel(
    const float* __restrict__ q, const float* __restrict__ k, const float* __restrict__ v,
    const bf16* __restrict__ Wb,
    const float* __restrict__ bq, const float* __restrict__ bk, const float* __restrict__ bv,
    bf16* __restrict__ Qw, bf16* __restrict__ Kw, bf16* __restrict__ Vw)
{
  const int z = blockIdx.z;
  const float* A = (z == 0) ? q : (z == 1) ? k : v;
  const bf16* W  = Wb + (size_t)z * 1048576;
  const float* B = (z == 0) ? bq : (z == 1) ? bk : bv;
  if (z == 2)      gemm_body(A, nullptr, W, B, Vw, 2, 1.0f);
  else if (z == 1) gemm_body(A, nullptr, W, B, Kw, 0, 1.0f);
  else             gemm_body(A, nullptr, W, B, Qw, 0, CEXP);
}

__global__ __launch_bounds__(256) void out_kernel(
    const bf16* __restrict__ Sb, const bf16* __restrict__ Wob,
    const float* __restrict__ bo, float* __restrict__ out)
{
  gemm_body(nullptr, Sb, Wob, bo, out, 1, 1.0f);
}

// ---------------------------------------------------------------------------
// Flash attention, no-max softmax. Block = 64 q x 64-key tiles, 4 waves;
// wave owns one 16-q subtile. Grid = 1024 blocks -> 4 blocks/CU (16 waves/CU,
// 2x previous occupancy). S^T = K Q^T operand-swap: per-lane q=mlane.
// Row sums via ones-column MFMA: lands in the same C/D layout as O
// (row=quad*4+r), so normalization needs no cross-lane shuffles.
// XCD swizzle: XCD k (g%8) owns bh in [4k,4k+4) -> K/V working set 2MB < L2.
// Writes scores fp32 (output) AND bf16 copy (for out_kernel's A-path).
// ---------------------------------------------------------------------------
__global__ __launch_bounds__(256) void attn_kernel(
    const bf16* __restrict__ Qw, const bf16* __restrict__ Kw,
    const bf16* __restrict__ Vtg, float* __restrict__ scores,
    bf16* __restrict__ Sb)
{
  __shared__ __align__(16) bf16 Ks[64 * 72];    // [key][dk]
  __shared__ __align__(16) bf16 Vt[64 * 72];    // [dk][key]
  __shared__ __align__(16) bf16 Ps[4][16 * 72]; // per-wave P [q(16)][key(64)]

  const int tid  = threadIdx.x;
  const int wave = tid >> 6;
  const int lane = tid & 63;
  const int mlane = lane & 15;
  const int quad  = lane >> 4;

  // bijective XCD-aware swizzle over 1024 blocks
  const int g = blockIdx.x + (blockIdx.y << 5);
  const int slot = g >> 3;
  const int bh = ((g & 7) << 2) + (slot >> 5);  // XCD g%8 gets 4 heads
  const int q0 = (slot & 31) << 6;
  const size_t base = (size_t)bh << 17;         // bh * 2048 * 64

  const int srow = tid >> 3, sc8 = (tid & 7) * 8;

  // Q B-frags (loop-invariant): q = q0 + wave*16 + mlane
  bf16x8 qf[2];
#pragma unroll
  for (int c = 0; c < 2; ++c)
    qf[c] = *(const bf16x8*)
        &Qw[base + (size_t)(q0 + wave * 16 + mlane) * 64 + c * 32 + quad * 8];

  bf16x8 ones;
#pragma unroll
  for (int j = 0; j < 8; ++j) ones[j] = (bf16)1.0f;

  floatx4 o[4] = {};
  floatx4 osum = {};

  bf16x8 kpf[2], vpf[2];
  auto load_kv = [&](int kt) {
#pragma unroll
    for (int rr = 0; rr < 2; ++rr) {
      const int row = rr * 32 + srow;
      kpf[rr] = *(const bf16x8*)&Kw[base + (size_t)(kt + row) * 64 + sc8];
      vpf[rr] = *(const bf16x8*)&Vtg[base + (size_t)row * 2048 + kt + sc8];
    }
  };
  load_kv(0);

  for (int kt = 0; kt < 2048; kt += 64) {
    __syncthreads();
#pragma unroll
    for (int rr = 0; rr < 2; ++rr) {
      const int row = rr * 32 + srow;
      *(bf16x8*)&Ks[row * 72 + sc8] = kpf[rr];
      *(bf16x8*)&Vt[row * 72 + sc8] = vpf[rr];
    }
    __syncthreads();
    if (kt + 64 < 2048) load_kv(kt + 64);

    // S^T = K Q^T
#pragma unroll
    for (int nt = 0; nt < 4; ++nt) {
      bf16x8 a0 = *(const bf16x8*)&Ks[(nt * 16 + mlane) * 72 + quad * 8];
      bf16x8 a1 = *(const bf16x8*)&Ks[(nt * 16 + mlane) * 72 + 32 + quad * 8];
      floatx4 s0 = {};
      __builtin_amdgcn_s_setprio(1);
      s0 = __builtin_amdgcn_mfma_f32_16x16x32_bf16(a0, qf[0], s0, 0, 0, 0);
      s0 = __builtin_amdgcn_mfma_f32_16x16x32_bf16(a1, qf[1], s0, 0, 0, 0);
      __builtin_amdgcn_s_setprio(0);
      bf16x4 pk;
#pragma unroll
      for (int r = 0; r < 4; ++r) pk[r] = (bf16)exp2f(s0[r]);
      *(bf16x4*)&Ps[wave][mlane * 72 + nt * 16 + quad * 4] = pk;
    }

    asm volatile("s_waitcnt lgkmcnt(0)" ::: "memory");

    // row-sum (ones-MFMA) + O += P V
    bf16x8 pa0 = *(const bf16x8*)&Ps[wave][mlane * 72 + quad * 8];
    bf16x8 pa1 = *(const bf16x8*)&Ps[wave][mlane * 72 + 32 + quad * 8];
    __builtin_amdgcn_s_setprio(1);
    osum = __builtin_amdgcn_mfma_f32_16x16x32_bf16(pa0, ones, osum, 0, 0, 0);
    osum = __builtin_amdgcn_mfma_f32_16x16x32_bf16(pa1, ones, osum, 0, 0, 0);
#pragma unroll
    for (int nt = 0; nt < 4; ++nt) {
      bf16x8 vb0 = *(const bf16x8*)&Vt[(nt * 16 + mlane) * 72 + quad * 8];
      bf16x8 vb1 = *(const bf16x8*)&Vt[(nt * 16 + mlane) * 72 + 32 + quad * 8];
      o[nt] = __builtin_amdgcn_mfma_f32_16x16x32_bf16(pa0, vb0, o[nt], 0, 0, 0);
      o[nt] = __builtin_amdgcn_mfma_f32_16x16x32_bf16(pa1, vb1, o[nt], 0, 0, 0);
    }
    __builtin_amdgcn_s_setprio(0);
  }

  // normalize: osum[r] is Σp for row quad*4+r — same layout as o[nt][r].
#pragma unroll
  for (int r = 0; r < 4; ++r) {
    const float inv = 1.0f / osum[r];
    const int row = q0 + wave * 16 + quad * 4 + r;
#pragma unroll
    for (int nt = 0; nt < 4; ++nt) {
      const float val = o[nt][r] * inv;
      const size_t idx = base + (size_t)row * 64 + nt * 16 + mlane;
      scores[idx] = val;
      Sb[idx] = (bf16)val;
    }
  }
}

// ---------------------------------------------------------------------------
extern "C" void kernel_launch(void* const* d_in, const int* in_sizes, int n_in,
                              void* d_out, int out_size, void* d_ws, size_t ws_size,
                              hipStream_t stream) {
  const float* query = (const float*)d_in[0];
  const float* key   = (const float*)d_in[1];
  const float* value = (const float*)d_in[2];
  const float* Wq = (const float*)d_in[3];
  const float* bq = (const float*)d_in[4];
  const float* Wk = (const float*)d_in[5];
  const float* bk = (const float*)d_in[6];
  const float* Wv = (const float*)d_in[7];
  const float* bv = (const float*)d_in[8];
  const float* Wo = (const float*)d_in[9];
  const float* bo = (const float*)d_in[10];

  float* out    = (float*)d_out;
  float* scores = out + (size_t)4194304;   // second output (fp32)

  bf16* Wb  = (bf16*)d_ws;                 // 8 MB (Wq,Wk,Wv,Wo bf16)
  bf16* Qws = Wb + (size_t)4194304;        // [b,h,s,dk], pre-scaled by CEXP
  bf16* Kws = Qws + (size_t)4194304;       // [b,h,s,dk]
  bf16* Vws = Kws + (size_t)4194304;       // [b,h,dk,s] (transposed)
  bf16* Sb  = Vws + (size_t)4194304;       // bf16 copy of scores

  wcvt_kernel<<<dim3(1024, 4), 256, 0, stream>>>(Wq, Wk, Wv, Wo, Wb);
  qkv_kernel<<<dim3(32, 8, 3), 256, 0, stream>>>(query, key, value, Wb,
                                                 bq, bk, bv, Qws, Kws, Vws);
  attn_kernel<<<dim3(32, 32), 256, 0, stream>>>(Qws, Kws, Vws, scores, Sb);
  out_kernel<<<dim3(32, 8), 256, 0, stream>>>(Sb, Wb + (size_t)3145728, bo, out);
}